// Round 10
// baseline (806.656 us; speedup 1.0000x reference)
//
#include <hip/hip_runtime.h>

#define NN 8192
#define SS 64
#define BSD 512                 // B*S
#define NS (NN*SS)              // 524288
#define NBS (NN*BSD)            // 4194304

typedef __attribute__((ext_vector_type(4))) _Float16 f16x4;
typedef __attribute__((ext_vector_type(8))) _Float16 f16x8;
typedef __attribute__((ext_vector_type(4))) float f32x4;

#define GLOAD_LDS16(gptr, lptr) \
    __builtin_amdgcn_global_load_lds((const __attribute__((address_space(1))) void*)(gptr), \
                                     (__attribute__((address_space(3))) void*)(lptr), 16, 0, 0)

// claimed (lane,elem)->k map inside a 32-k chunk; only needs to be identical
// for A and B packs (self-canceling bijection in the MFMA dot product).
// Empirically validated by rounds 3/5/6/7/8/9 with random asymmetric Mix.
__device__ __forceinline__ int kmap(int lane, int e) {
    return ((lane >> 4) << 2) + (e & 3) + ((e >> 2) << 4);
}

// ---------------------------------------------------------------- gate
__global__ void sigmoid_gate_kernel(const float* __restrict__ ent, float* __restrict__ gate) {
    int i = blockIdx.x * 256 + threadIdx.x;
    gate[i] = 1.0f / (1.0f + expf(-ent[i]));
}

// ================================================================= convA
// D[k][m] = Mix[k][m] - (k==m), split hi/lo f16.
// 64-row tiles: tile(mt64,kt) at (mt64*128+kt)*16384: hi 8KB [blk4][kk2][lane][16B], lo +8192.
__global__ __launch_bounds__(256) void convA_kernel(const float* __restrict__ Mx,
                                                    char* __restrict__ Ab) {
    __shared__ _Float16 Lh[64][136];
    __shared__ _Float16 Ll[64][136];
    const int t = threadIdx.x;
    const int kt = blockIdx.x, mt = blockIdx.y;   // mt: 128-col group (0..63)
    const int k0 = kt * 64, m0 = mt * 128;
    #pragma unroll
    for (int i = 0; i < 8; ++i) {
        int e = i * 256 + t;
        int kr = e >> 5, m4 = (e & 31) << 2;
        float4 v = *(const float4*)&Mx[(size_t)(k0 + kr) * NN + m0 + m4];
        int d = (k0 + kr) - (m0 + m4);     // subtract identity where k == m
        if (d == 0) v.x -= 1.0f;
        if (d == 1) v.y -= 1.0f;
        if (d == 2) v.z -= 1.0f;
        if (d == 3) v.w -= 1.0f;
        f16x4 h, l;
        h[0] = (_Float16)v.x; l[0] = (_Float16)(v.x - (float)h[0]);
        h[1] = (_Float16)v.y; l[1] = (_Float16)(v.y - (float)h[1]);
        h[2] = (_Float16)v.z; l[2] = (_Float16)(v.z - (float)h[2]);
        h[3] = (_Float16)v.w; l[3] = (_Float16)(v.w - (float)h[3]);
        *(f16x4*)&Lh[kr][m4] = h;
        *(f16x4*)&Ll[kr][m4] = l;
    }
    __syncthreads();
    #pragma unroll
    for (int j = 0; j < 4; ++j) {
        int idx  = j * 256 + t;            // 0..1023
        int h    = idx >> 9;               // which 64-row half
        int w    = idx & 511;              // [blk4][kk2][lane64]
        int blk  = w >> 7;
        int kk   = (w >> 6) & 1;
        int lane = w & 63;
        int col  = h * 64 + blk * 16 + (lane & 15);
        int kb   = kk * 32;
        f16x8 hv, lv;
        #pragma unroll
        for (int e = 0; e < 8; ++e) {
            int k = kb + kmap(lane, e);
            hv[e] = Lh[k][col];
            lv[e] = Ll[k][col];
        }
        char* tile = Ab + (((size_t)(mt * 2 + h) * 128 + kt) << 14);
        *(f16x8*)(tile + w * 16)        = hv;
        *(f16x8*)(tile + 8192 + w * 16) = lv;
    }
}

// ---------------------------------------------------------------- shared B pack
__device__ __forceinline__ void pack_B(const _Float16 (*Lh)[520],
                                       const _Float16 (*Nh)[72], const _Float16 (*Nl)[72],
                                       char* Bb, char* Nb, int kt, int t) {
    #pragma unroll
    for (int j = 0; j < 16; ++j) {
        int idx = j * 256 + t;             // 0..4095
        int nbt = idx >> 10, w = idx & 1023;
        int blk = w >> 7, kk = (w >> 6) & 1, lane = w & 63;
        int col = nbt * 128 + blk * 16 + (lane & 15);
        int kb = kk * 32;
        f16x8 hv;
        #pragma unroll
        for (int e = 0; e < 8; ++e)
            hv[e] = Lh[kb + kmap(lane, e)][col];
        *(f16x8*)(Bb + (((size_t)kt * 4 + nbt) << 14) + w * 16) = hv;
    }
    #pragma unroll
    for (int j = 0; j < 4; ++j) {
        int idx = j * 256 + t;             // 0..1023
        int nbt = idx >> 8, r = idx & 255;
        int part = r >> 7, kk = (r >> 6) & 1, lane = r & 63;
        int s = nbt * 16 + (lane & 15);
        int kb = kk * 32;
        f16x8 v;
        #pragma unroll
        for (int e = 0; e < 8; ++e) {
            int k = kb + kmap(lane, e);
            v[e] = part ? Nl[k][s] : Nh[k][s];
        }
        *(f16x8*)(Nb + (((size_t)kt * 4 + nbt) << 12) + part * 2048 + kk * 1024 + lane * 16) = v;
    }
}

// ================================================================= prep0 (layer 1 B)
__global__ __launch_bounds__(256) void prep0_kernel(const float* __restrict__ x,
                                                    const float* __restrict__ gate,
                                                    float* __restrict__ X,
                                                    char* __restrict__ Bb,
                                                    char* __restrict__ Nb,
                                                    float* __restrict__ mg32) {
    __shared__ _Float16 Lh[64][520];
    __shared__ _Float16 Nh[64][72];
    __shared__ _Float16 Nl[64][72];
    const int t = threadIdx.x;
    const int kt = blockIdx.x;
    const int n0 = kt * 64;
    #pragma unroll
    for (int i = 0; i < 4; ++i) {
        int e = i * 256 + t;           // 0..1023
        int kr = e >> 4;               // 0..63
        int s4 = (e & 15) << 2;        // 0..60
        float4 g = *(const float4*)&gate[(size_t)(n0 + kr) * 64 + s4];
        float4 ms = make_float4(0.f, 0.f, 0.f, 0.f);
        #pragma unroll
        for (int b = 0; b < 8; ++b) {
            float4 v = *(const float4*)&x[((size_t)b * NN + n0 + kr) * 64 + s4];
            ms.x += v.x; ms.y += v.y; ms.z += v.z; ms.w += v.w;
            v.x *= g.x; v.y *= g.y; v.z *= g.z; v.w *= g.w;
            *(float4*)&X[(size_t)(n0 + kr) * BSD + b * 64 + s4] = v;
            f16x4 h;
            h[0] = (_Float16)v.x; h[1] = (_Float16)v.y;
            h[2] = (_Float16)v.z; h[3] = (_Float16)v.w;
            *(f16x4*)&Lh[kr][b * 64 + s4] = h;
        }
        float4 mg4;
        mg4.x = ms.x * 0.125f * g.x; mg4.y = ms.y * 0.125f * g.y;
        mg4.z = ms.z * 0.125f * g.z; mg4.w = ms.w * 0.125f * g.w;
        *(float4*)&mg32[(size_t)(n0 + kr) * 64 + s4] = mg4;
        f16x4 mh, ml;
        mh[0] = (_Float16)mg4.x; ml[0] = (_Float16)(mg4.x - (float)mh[0]);
        mh[1] = (_Float16)mg4.y; ml[1] = (_Float16)(mg4.y - (float)mh[1]);
        mh[2] = (_Float16)mg4.z; ml[2] = (_Float16)(mg4.z - (float)mh[2]);
        mh[3] = (_Float16)mg4.w; ml[3] = (_Float16)(mg4.w - (float)mh[3]);
        *(f16x4*)&Nh[kr][s4] = mh;
        *(f16x4*)&Nl[kr][s4] = ml;
    }
    __syncthreads();
    pack_B(Lh, Nh, Nl, Bb, Nb, kt, t);
}

// ================================================================= gateconv (layers 2,3 B)
// xnew = X + P0 + P1 (P0/P1 nullable);  X <- xnew*gate;  pack Bmain.
// nsl  = mg32 + Np0 + Np1 (if Np0) else nsfull;  nsf <- nsl (main mode);
// mg32 <- nsl*gate;  pack Bns.
__global__ __launch_bounds__(256) void gateconv_kernel(float* __restrict__ X,
                                                       const float* __restrict__ P0,
                                                       const float* __restrict__ P1,
                                                       const float* __restrict__ gate,
                                                       float* __restrict__ mg32,
                                                       const float* __restrict__ Np0,
                                                       const float* __restrict__ Np1,
                                                       float* __restrict__ nsf,
                                                       char* __restrict__ Bb,
                                                       char* __restrict__ Nb) {
    __shared__ _Float16 Lh[64][520];
    __shared__ _Float16 Nh[64][72];
    __shared__ _Float16 Nl[64][72];
    const int t = threadIdx.x;
    const int kt = blockIdx.x;
    const int n0 = kt * 64;
    #pragma unroll
    for (int i = 0; i < 32; ++i) {
        int e = i * 256 + t;           // 0..8191
        int kr = e >> 7;               // 0..63
        int c4 = (e & 127) << 2;       // 0..508
        size_t idx = (size_t)(n0 + kr) * BSD + c4;
        float4 v = *(const float4*)&X[idx];
        if (P0) {
            float4 p = *(const float4*)&P0[idx];
            v.x += p.x; v.y += p.y; v.z += p.z; v.w += p.w;
        }
        if (P1) {
            float4 p = *(const float4*)&P1[idx];
            v.x += p.x; v.y += p.y; v.z += p.z; v.w += p.w;
        }
        float4 g = *(const float4*)&gate[(size_t)(n0 + kr) * 64 + (c4 & 63)];
        v.x *= g.x; v.y *= g.y; v.z *= g.z; v.w *= g.w;
        *(float4*)&X[idx] = v;
        f16x4 h;
        h[0] = (_Float16)v.x; h[1] = (_Float16)v.y;
        h[2] = (_Float16)v.z; h[3] = (_Float16)v.w;
        *(f16x4*)&Lh[kr][c4] = h;
    }
    #pragma unroll
    for (int i = 0; i < 4; ++i) {
        int e = i * 256 + t;
        int kr = e >> 4;
        int s4 = (e & 15) << 2;
        size_t nidx = (size_t)(n0 + kr) * 64 + s4;
        float4 p;
        if (Np0) {
            p = *(const float4*)&mg32[nidx];
            float4 a = *(const float4*)&Np0[nidx];
            p.x += a.x; p.y += a.y; p.z += a.z; p.w += a.w;
            if (Np1) {
                float4 b2 = *(const float4*)&Np1[nidx];
                p.x += b2.x; p.y += b2.y; p.z += b2.z; p.w += b2.w;
            }
            *(float4*)&nsf[nidx] = p;               // finalized ns_l
        } else {
            p = *(const float4*)&nsf[nidx];         // fallback: already final
        }
        float4 g = *(const float4*)&gate[nidx];
        float4 mg4;
        mg4.x = p.x * g.x; mg4.y = p.y * g.y; mg4.z = p.z * g.z; mg4.w = p.w * g.w;
        *(float4*)&mg32[nidx] = mg4;
        f16x4 mh, ml;
        mh[0] = (_Float16)mg4.x; ml[0] = (_Float16)(mg4.x - (float)mh[0]);
        mh[1] = (_Float16)mg4.y; ml[1] = (_Float16)(mg4.y - (float)mh[1]);
        mh[2] = (_Float16)mg4.z; ml[2] = (_Float16)(mg4.z - (float)mh[2]);
        mh[3] = (_Float16)mg4.w; ml[3] = (_Float16)(mg4.w - (float)mh[3]);
        *(f16x4*)&Nh[kr][s4] = mh;
        *(f16x4*)&Nl[kr][s4] = ml;
    }
    __syncthreads();
    pack_B(Lh, Nh, Nl, Bb, Nb, kt, t);
}

// ================================================================= GEMM (K-split partial)
// P[kb][m][c] = sum_{k in half kb} Dh[k][m]*Yg_f16[k][c]
// Np[kb][m][s] = sum_{k in half kb} (Dh*mh + Dh*ml + Dl*mh)[m][s]
// Block 64x(128+16ns), BK=64, nkt=64, 4 waves; grid 1024 -> 4 blocks/CU.
// A hi+lo via LDS (dbuf 2x16KB); B-main + B-ns direct L2->VGPR (reg dbuf).
__global__ __launch_bounds__(256, 4) void gemm_split_kernel(const char* __restrict__ Ab,
                                                            const char* __restrict__ Bb,
                                                            const char* __restrict__ Nb,
                                                            float* __restrict__ Pp,
                                                            float* __restrict__ Npp) {
    __shared__ char lds[2][16384];   // Ahi 8K | Alo 8K
    const int t = threadIdx.x;
    int L = blockIdx.x;                          // 0..1023
    const int kb = L >> 9;                       // K half
    L &= 511;
    const int mt  = (L & 7) + ((L >> 5) << 3);   // 0..127 (64-row tile idx)
    const int nbt = (L >> 3) & 3;                // 0..3
    const int lane = t & 63, wid = t >> 6;       // 4 waves; wave cols = wid*32
    const int kt0 = kb * 64;

    const char* gA = Ab + (((size_t)mt * 128 + kt0) << 14) + wid * 2048 + lane * 16;
    const char* gB = Bb + (((size_t)kt0 * 4 + nbt) << 14) + wid * 4096 + lane * 16;
    const char* gN = Nb + (((size_t)kt0 * 4 + nbt) << 12) + lane * 16;
    const uint32_t lA = wid * 2048;

    auto stageA = [&](char* la, const char* pA) {
        GLOAD_LDS16(pA,               la + lA);
        GLOAD_LDS16(pA + 1024,        la + lA + 1024);
        GLOAD_LDS16(pA + 8192,        la + lA + 8192);
        GLOAD_LDS16(pA + 8192 + 1024, la + lA + 8192 + 1024);
    };   // 4 VMEM per wave

    f16x8 B0[4], B1[4];      // main B: [kk + 2*fj]
    auto loadB = [&](f16x8* Br, const char* pB) {
        Br[0] = *(const f16x8*)(pB);
        Br[1] = *(const f16x8*)(pB + 1024);
        Br[2] = *(const f16x8*)(pB + 2048);
        Br[3] = *(const f16x8*)(pB + 3072);
    };   // 4 VMEM per wave
    f16x8 N0[4], N1[4];      // ns B: [h kk0, h kk1, l kk0, l kk1]
    auto loadN = [&](f16x8* Nr, const char* pN) {
        Nr[0] = *(const f16x8*)(pN);
        Nr[1] = *(const f16x8*)(pN + 1024);
        Nr[2] = *(const f16x8*)(pN + 2048);
        Nr[3] = *(const f16x8*)(pN + 3072);
    };   // 4 VMEM per wave

    f32x4 accm[4][2];
    #pragma unroll
    for (int fi = 0; fi < 4; ++fi) {
        accm[fi][0] = (f32x4){0.f, 0.f, 0.f, 0.f};
        accm[fi][1] = (f32x4){0.f, 0.f, 0.f, 0.f};
    }
    f32x4 accn = (f32x4){0.f, 0.f, 0.f, 0.f};

    auto compute = [&](const char* base, const f16x8* Br, const f16x8* Nr) {
        const char* A_ = base + lane * 16;          // +fi*2048+kk*1024 (+8192 lo)
        #pragma unroll
        for (int kk = 0; kk < 2; ++kk) {
            const int ko = kk * 1024;
            #pragma unroll
            for (int fi = 0; fi < 4; ++fi) {
                f16x8 ah = *(const f16x8*)(A_ + fi * 2048 + ko);
                accm[fi][0] = __builtin_amdgcn_mfma_f32_16x16x32_f16(ah, Br[kk],     accm[fi][0], 0, 0, 0);
                accm[fi][1] = __builtin_amdgcn_mfma_f32_16x16x32_f16(ah, Br[2 + kk], accm[fi][1], 0, 0, 0);
                if (fi == wid) {             // wave-uniform: ns rows = this wave's fi block
                    f16x8 aln = *(const f16x8*)(A_ + 8192 + fi * 2048 + ko);
                    accn = __builtin_amdgcn_mfma_f32_16x16x32_f16(ah,  Nr[kk],     accn, 0, 0, 0);
                    accn = __builtin_amdgcn_mfma_f32_16x16x32_f16(ah,  Nr[2 + kk], accn, 0, 0, 0);
                    accn = __builtin_amdgcn_mfma_f32_16x16x32_f16(aln, Nr[kk],     accn, 0, 0, 0);
                }
            }
        }
    };

    stageA(lds[0], gA);
    loadB(B0, gB);
    loadN(N0, gN);
    gA += 16384; gB += 65536; gN += 16384;

    for (int u = 0; u < 32; ++u) {
        // ---- even kt: compute lds[0]+B0+N0, prefetch lds[1]+B1+N1
        asm volatile("s_waitcnt vmcnt(0)" ::: "memory");
        __builtin_amdgcn_s_barrier();
        __builtin_amdgcn_sched_barrier(0);
        stageA(lds[1], gA);
        loadB(B1, gB);
        loadN(N1, gN);
        gA += 16384; gB += 65536; gN += 16384;
        __builtin_amdgcn_sched_barrier(0);
        compute(lds[0], B0, N0);
        // ---- odd kt: compute lds[1]+B1+N1, prefetch lds[0]+B0+N0
        asm volatile("s_waitcnt vmcnt(0)" ::: "memory");
        __builtin_amdgcn_s_barrier();
        __builtin_amdgcn_sched_barrier(0);
        if (u < 31) {
            stageA(lds[0], gA);
            loadB(B0, gB);
            loadN(N0, gN);
            gA += 16384; gB += 65536; gN += 16384;
        }
        __builtin_amdgcn_sched_barrier(0);
        compute(lds[1], B1, N1);
    }

    float* P  = Pp  + (size_t)kb * NBS;
    float* Np = Npp + (size_t)kb * NS;
    // D layout (m89-verified): col = lane&15, row = (lane>>4)*4 + reg
    const int row0 = mt * 64 + ((lane >> 4) << 2);
    const int col0 = nbt * 128 + wid * 32 + (lane & 15);
    #pragma unroll
    for (int fi = 0; fi < 4; ++fi)
        #pragma unroll
        for (int fj = 0; fj < 2; ++fj)
            #pragma unroll
            for (int j = 0; j < 4; ++j)
                P[(size_t)(row0 + fi * 16 + j) * BSD + col0 + fj * 16] = accm[fi][fj][j];
    const int nr0 = mt * 64 + wid * 16 + ((lane >> 4) << 2);
    const int nc  = nbt * 16 + (lane & 15);
    #pragma unroll
    for (int j = 0; j < 4; ++j)
        Np[(size_t)(nr0 + j) * 64 + nc] = accn[j];
}

// ================================================================= GEMM (fallback, R9 in-place)
__global__ __launch_bounds__(256) void gemm_inplace_kernel(const char* __restrict__ Ab,
                                                           const char* __restrict__ Bb,
                                                           const char* __restrict__ Nb,
                                                           float* X,
                                                           const float* __restrict__ mg,
                                                           float* __restrict__ nsout) {
    __shared__ char lds[2][20480];   // Ahi 8K | Alo 8K | Bns 4K
    const int t = threadIdx.x;
    const int L = blockIdx.x;
    const int mt  = (L & 7) + ((L >> 5) << 3);
    const int nbt = (L >> 3) & 3;
    const int lane = t & 63, wid = t >> 6;
    const char* gA = Ab + (((size_t)mt * 128) << 14) + wid * 2048 + lane * 16;
    const char* gB = Bb + (((size_t)nbt) << 14) + wid * 4096 + lane * 16;
    const char* gN = Nb + (((size_t)nbt) << 12) + wid * 1024 + lane * 16;
    const uint32_t lA = wid * 2048;
    const uint32_t lN = 16384 + wid * 1024;
    auto stageA = [&](char* la, const char* pA, const char* pN) {
        GLOAD_LDS16(pA,               la + lA);
        GLOAD_LDS16(pA + 1024,        la + lA + 1024);
        GLOAD_LDS16(pA + 8192,        la + lA + 8192);
        GLOAD_LDS16(pA + 8192 + 1024, la + lA + 8192 + 1024);
        GLOAD_LDS16(pN,               la + lN);
    };
    f16x8 B0[4], B1[4];
    auto loadB = [&](f16x8* Br, const char* pB) {
        Br[0] = *(const f16x8*)(pB);
        Br[1] = *(const f16x8*)(pB + 1024);
        Br[2] = *(const f16x8*)(pB + 2048);
        Br[3] = *(const f16x8*)(pB + 3072);
    };
    f32x4 accm[4][2];
    #pragma unroll
    for (int fi = 0; fi < 4; ++fi) {
        accm[fi][0] = (f32x4){0.f, 0.f, 0.f, 0.f};
        accm[fi][1] = (f32x4){0.f, 0.f, 0.f, 0.f};
    }
    f32x4 accn = (f32x4){0.f, 0.f, 0.f, 0.f};
    auto compute = [&](const char* base, const f16x8* Br) {
        const char* A_ = base + lane * 16;
        const char* Bn = base + 16384 + lane * 16;
        #pragma unroll
        for (int kk = 0; kk < 2; ++kk) {
            const int ko = kk * 1024;
            f16x8 bnh = *(const f16x8*)(Bn + ko);
            f16x8 bnl = *(const f16x8*)(Bn + 2048 + ko);
            #pragma unroll
            for (int fi = 0; fi < 4; ++fi) {
                f16x8 ah = *(const f16x8*)(A_ + fi * 2048 + ko);
                accm[fi][0] = __builtin_amdgcn_mfma_f32_16x16x32_f16(ah, Br[kk],     accm[fi][0], 0, 0, 0);
                accm[fi][1] = __builtin_amdgcn_mfma_f32_16x16x32_f16(ah, Br[2 + kk], accm[fi][1], 0, 0, 0);
                if (fi == wid) {
                    f16x8 aln = *(const f16x8*)(A_ + 8192 + fi * 2048 + ko);
                    accn = __builtin_amdgcn_mfma_f32_16x16x32_f16(ah,  bnh, accn, 0, 0, 0);
                    accn = __builtin_amdgcn_mfma_f32_16x16x32_f16(ah,  bnl, accn, 0, 0, 0);
                    accn = __builtin_amdgcn_mfma_f32_16x16x32_f16(aln, bnh, accn, 0, 0, 0);
                }
            }
        }
    };
    stageA(lds[0], gA, gN);
    loadB(B0, gB);
    gA += 16384; gN += 16384; gB += 65536;
    for (int u = 0; u < 64; ++u) {
        asm volatile("s_waitcnt vmcnt(0)" ::: "memory");
        __builtin_amdgcn_s_barrier();
        __builtin_amdgcn_sched_barrier(0);
        stageA(lds[1], gA, gN);
        loadB(B1, gB);
        gA += 16384; gN += 16384; gB += 65536;
        __builtin_amdgcn_sched_barrier(0);
        compute(lds[0], B0);
        asm volatile("s_waitcnt vmcnt(0)" ::: "memory");
        __builtin_amdgcn_s_barrier();
        __builtin_amdgcn_sched_barrier(0);
        if (u < 63) {
            stageA(lds[0], gA, gN);
            loadB(B0, gB);
            gA += 16384; gN += 16384; gB += 65536;
        }
        __builtin_amdgcn_sched_barrier(0);
        compute(lds[1], B1);
    }
    const int row0 = mt * 64 + ((lane >> 4) << 2);
    const int col0 = nbt * 128 + wid * 32 + (lane & 15);
    #pragma unroll
    for (int fi = 0; fi < 4; ++fi)
        #pragma unroll
        for (int fj = 0; fj < 2; ++fj)
            #pragma unroll
            for (int j = 0; j < 4; ++j) {
                size_t idx = (size_t)(row0 + fi * 16 + j) * BSD + col0 + fj * 16;
                X[idx] = accm[fi][fj][j] + X[idx];
            }
    const int nr0 = mt * 64 + wid * 16 + ((lane >> 4) << 2);
    const int nc  = nbt * 16 + (lane & 15);
    #pragma unroll
    for (int j = 0; j < 4; ++j) {
        size_t nidx = (size_t)(nr0 + j) * 64 + nc;
        nsout[nidx] = accn[j] + mg[nidx];
    }
}

// ================================================================= readout
__global__ __launch_bounds__(256) void readout_kernel(const float* __restrict__ X3,
                                                      const float* __restrict__ P0,
                                                      const float* __restrict__ P1,
                                                      const float* __restrict__ W,
                                                      float* __restrict__ out) {
    __shared__ float Wt[64][65];
    __shared__ float xr[512];
    const int n = blockIdx.x;
    const int t = threadIdx.x;
    for (int e = t; e < 4096; e += 256) {
        int s = e >> 6, sp = e & 63;
        Wt[sp][s] = W[e];
    }
    size_t i0 = (size_t)n * BSD + t;
    size_t i1 = i0 + 256;
    float a = X3[i0], b = X3[i1];
    if (P0) { a += P0[i0]; b += P0[i1]; }
    if (P1) { a += P1[i0]; b += P1[i1]; }
    xr[t] = a; xr[t + 256] = b;
    __syncthreads();
    const int b1 = t >> 6;
    const int s  = t & 63;
    float acc0 = 0.0f, acc1 = 0.0f;
    #pragma unroll
    for (int sp = 0; sp < 64; ++sp) {
        float w = Wt[sp][s];
        acc0 += w * xr[b1 * 64 + sp];
        acc1 += w * xr[(b1 + 4) * 64 + sp];
    }
    out[((size_t)b1 * NN + n) * SS + s]       = acc0;
    out[((size_t)(b1 + 4) * NN + n) * SS + s] = acc1;
}

// ================================== temporal avg + enc + dec + top-k collapse
__global__ void nsfinal_kernel(const float* __restrict__ ns1,
                               const float* __restrict__ ns2,
                               const float* __restrict__ mg3,   // or final ns3 (fallback)
                               const float* __restrict__ Np0,
                               const float* __restrict__ Np1,
                               const float* __restrict__ enc_w, const float* __restrict__ enc_b,
                               const float* __restrict__ dec_w, const float* __restrict__ dec_b,
                               float* __restrict__ out_ns) {
    int gtid = blockIdx.x * 256 + threadIdx.x;
    int lane = gtid & 63;
    const float r = 0.9f;
    const float wsum = 1.0f + r + r * r;
    float n3 = mg3[gtid];
    if (Np0) n3 += Np0[gtid];
    if (Np1) n3 += Np1[gtid];
    float tns = (ns1[gtid] * (r * r) + ns2[gtid] * r + n3) / wsum;
    float v = dec_b[lane];
    #pragma unroll
    for (int c = 0; c < 16; ++c) {
        float p = tns * enc_w[c * 64 + lane];
        #pragma unroll
        for (int off = 32; off; off >>= 1) p += __shfl_xor(p, off, 64);
        float h = fmaxf(p + enc_b[c], 0.0f);
        v += h * dec_w[lane * 16 + c];
    }
    float av = fabsf(v);
    int cnt = 0;
    for (int j = 0; j < 64; ++j) {
        float o = __shfl(av, j, 64);
        cnt += (o > av) ? 1 : 0;
    }
    out_ns[gtid] = (cnt < 8) ? v : 0.0f;
}

// ================================================================= launch
extern "C" void kernel_launch(void* const* d_in, const int* in_sizes, int n_in,
                              void* d_out, int out_size, void* d_ws, size_t ws_size,
                              hipStream_t stream) {
    const float* x      = (const float*)d_in[0];
    const float* ent    = (const float*)d_in[1];
    const float* mixing = (const float*)d_in[2];
    const float* r_w    = (const float*)d_in[3];
    const float* enc_w  = (const float*)d_in[4];
    const float* enc_b  = (const float*)d_in[5];
    const float* dec_w  = (const float*)d_in[6];
    const float* dec_b  = (const float*)d_in[7];
    float* out = (float*)d_out;

    char*  Ab   = (char*)d_ws;                    // 256 MB  (D hi|lo 64-row tiles)
    char*  Bb   = Ab + 268435456ull;              // 8 MB
    char*  Nb   = Bb + 8388608ull;                // 2 MB
    float* X    = (float*)(Nb + 2097152ull);      // 16 MB
    float* mg32 = X + NBS;                        // 2 MB
    float* ns0  = mg32 + NS;                      // 6 MB (3 layers)
    float* gate = ns0 + 3 * (size_t)NS;           // 2 MB
    float* Pp   = gate + NS;                      // 32 MB (2 K-half partials)
    float* Npp  = Pp + 2 * (size_t)NBS;           // 4 MB  (2 ns partials)
    const size_t NEED2 = (size_t)(Npp + 2 * (size_t)NS - (float*)d_ws) * 4;
    const bool split = ws_size >= NEED2;          // 328 MB; fallback uses 292 MB

    sigmoid_gate_kernel<<<NS / 256, 256, 0, stream>>>(ent, gate);
    convA_kernel<<<dim3(128, 64), 256, 0, stream>>>(mixing, Ab);
    prep0_kernel<<<128, 256, 0, stream>>>(x, gate, X, Bb, Nb, mg32);

    if (split) {
        for (int l = 0; l < 3; ++l) {
            gemm_split_kernel<<<1024, 256, 0, stream>>>(Ab, Bb, Nb, Pp, Npp);
            if (l < 2)
                gateconv_kernel<<<128, 256, 0, stream>>>(X, Pp, Pp + NBS, gate, mg32,
                                                         Npp, Npp + NS, ns0 + (size_t)l * NS,
                                                         Bb, Nb);
        }
        readout_kernel<<<NN, 256, 0, stream>>>(X, Pp, Pp + NBS, r_w, out);
        nsfinal_kernel<<<2048, 256, 0, stream>>>(ns0, ns0 + NS, mg32, Npp, Npp + NS,
                                                 enc_w, enc_b, dec_w, dec_b, out + NBS);
    } else {
        for (int l = 0; l < 3; ++l) {
            gemm_inplace_kernel<<<512, 256, 0, stream>>>(Ab, Bb, Nb, X, mg32,
                                                         ns0 + (size_t)l * NS);
            if (l < 2)
                gateconv_kernel<<<128, 256, 0, stream>>>(X, nullptr, nullptr, gate, mg32,
                                                         nullptr, nullptr, ns0 + (size_t)l * NS,
                                                         Bb, Nb);
        }
        readout_kernel<<<NN, 256, 0, stream>>>(X, nullptr, nullptr, r_w, out);
        nsfinal_kernel<<<2048, 256, 0, stream>>>(ns0, ns0 + NS, ns0 + 2 * (size_t)NS,
                                                 nullptr, nullptr,
                                                 enc_w, enc_b, dec_w, dec_b, out + NBS);
    }
}

// Round 11
// 759.380 us; speedup vs baseline: 1.0623x; 1.0623x over previous
//
#include <hip/hip_runtime.h>

#define NN 8192
#define SS 64
#define BSD 512                 // B*S
#define NS (NN*SS)              // 524288
#define NBS (NN*BSD)            // 4194304

typedef __attribute__((ext_vector_type(4))) _Float16 f16x4;
typedef __attribute__((ext_vector_type(8))) _Float16 f16x8;
typedef __attribute__((ext_vector_type(4))) float f32x4;

#define GLOAD_LDS16(gptr, lptr) \
    __builtin_amdgcn_global_load_lds((const __attribute__((address_space(1))) void*)(gptr), \
                                     (__attribute__((address_space(3))) void*)(lptr), 16, 0, 0)

// claimed (lane,elem)->k map inside a 32-k chunk; only needs to be identical
// for A and B packs (self-canceling bijection in the MFMA dot product).
// Empirically validated by rounds 3/5/6/7/8/9/10 with random asymmetric Mix.
__device__ __forceinline__ int kmap(int lane, int e) {
    return ((lane >> 4) << 2) + (e & 3) + ((e >> 2) << 4);
}

// ---------------------------------------------------------------- gate
__global__ void sigmoid_gate_kernel(const float* __restrict__ ent, float* __restrict__ gate) {
    int i = blockIdx.x * 256 + threadIdx.x;
    gate[i] = 1.0f / (1.0f + expf(-ent[i]));
}

// ================================================================= convA
// D[k][m] = Mix[k][m] - (k==m), split hi/lo f16.
// 64-row tiles: tile(mt64,kt) at (mt64*128+kt)*16384: hi 8KB [blk4][kk2][lane][16B], lo +8192.
__global__ __launch_bounds__(256) void convA_kernel(const float* __restrict__ Mx,
                                                    char* __restrict__ Ab) {
    __shared__ _Float16 Lh[64][136];
    __shared__ _Float16 Ll[64][136];
    const int t = threadIdx.x;
    const int kt = blockIdx.x, mt = blockIdx.y;   // mt: 128-col group (0..63)
    const int k0 = kt * 64, m0 = mt * 128;
    #pragma unroll
    for (int i = 0; i < 8; ++i) {
        int e = i * 256 + t;
        int kr = e >> 5, m4 = (e & 31) << 2;
        float4 v = *(const float4*)&Mx[(size_t)(k0 + kr) * NN + m0 + m4];
        int d = (k0 + kr) - (m0 + m4);     // subtract identity where k == m
        if (d == 0) v.x -= 1.0f;
        if (d == 1) v.y -= 1.0f;
        if (d == 2) v.z -= 1.0f;
        if (d == 3) v.w -= 1.0f;
        f16x4 h, l;
        h[0] = (_Float16)v.x; l[0] = (_Float16)(v.x - (float)h[0]);
        h[1] = (_Float16)v.y; l[1] = (_Float16)(v.y - (float)h[1]);
        h[2] = (_Float16)v.z; l[2] = (_Float16)(v.z - (float)h[2]);
        h[3] = (_Float16)v.w; l[3] = (_Float16)(v.w - (float)h[3]);
        *(f16x4*)&Lh[kr][m4] = h;
        *(f16x4*)&Ll[kr][m4] = l;
    }
    __syncthreads();
    #pragma unroll
    for (int j = 0; j < 4; ++j) {
        int idx  = j * 256 + t;            // 0..1023
        int h    = idx >> 9;               // which 64-row half
        int w    = idx & 511;              // [blk4][kk2][lane64]
        int blk  = w >> 7;
        int kk   = (w >> 6) & 1;
        int lane = w & 63;
        int col  = h * 64 + blk * 16 + (lane & 15);
        int kb   = kk * 32;
        f16x8 hv, lv;
        #pragma unroll
        for (int e = 0; e < 8; ++e) {
            int k = kb + kmap(lane, e);
            hv[e] = Lh[k][col];
            lv[e] = Ll[k][col];
        }
        char* tile = Ab + (((size_t)(mt * 2 + h) * 128 + kt) << 14);
        *(f16x8*)(tile + w * 16)        = hv;
        *(f16x8*)(tile + 8192 + w * 16) = lv;
    }
}

// ---------------------------------------------------------------- shared B pack
__device__ __forceinline__ void pack_B(const _Float16 (*Lh)[520],
                                       const _Float16 (*Nh)[72], const _Float16 (*Nl)[72],
                                       char* Bb, char* Nb, int kt, int t) {
    #pragma unroll
    for (int j = 0; j < 16; ++j) {
        int idx = j * 256 + t;             // 0..4095
        int nbt = idx >> 10, w = idx & 1023;
        int blk = w >> 7, kk = (w >> 6) & 1, lane = w & 63;
        int col = nbt * 128 + blk * 16 + (lane & 15);
        int kb = kk * 32;
        f16x8 hv;
        #pragma unroll
        for (int e = 0; e < 8; ++e)
            hv[e] = Lh[kb + kmap(lane, e)][col];
        *(f16x8*)(Bb + (((size_t)kt * 4 + nbt) << 14) + w * 16) = hv;
    }
    #pragma unroll
    for (int j = 0; j < 4; ++j) {
        int idx = j * 256 + t;             // 0..1023
        int nbt = idx >> 8, r = idx & 255;
        int part = r >> 7, kk = (r >> 6) & 1, lane = r & 63;
        int s = nbt * 16 + (lane & 15);
        int kb = kk * 32;
        f16x8 v;
        #pragma unroll
        for (int e = 0; e < 8; ++e) {
            int k = kb + kmap(lane, e);
            v[e] = part ? Nl[k][s] : Nh[k][s];
        }
        *(f16x8*)(Nb + (((size_t)kt * 4 + nbt) << 12) + part * 2048 + kk * 1024 + lane * 16) = v;
    }
}

// ================================================================= prep0 (layer 1 B)
__global__ __launch_bounds__(256) void prep0_kernel(const float* __restrict__ x,
                                                    const float* __restrict__ gate,
                                                    float* __restrict__ X,
                                                    char* __restrict__ Bb,
                                                    char* __restrict__ Nb,
                                                    float* __restrict__ mg32) {
    __shared__ _Float16 Lh[64][520];
    __shared__ _Float16 Nh[64][72];
    __shared__ _Float16 Nl[64][72];
    const int t = threadIdx.x;
    const int kt = blockIdx.x;
    const int n0 = kt * 64;
    #pragma unroll
    for (int i = 0; i < 4; ++i) {
        int e = i * 256 + t;           // 0..1023
        int kr = e >> 4;               // 0..63
        int s4 = (e & 15) << 2;        // 0..60
        float4 g = *(const float4*)&gate[(size_t)(n0 + kr) * 64 + s4];
        float4 ms = make_float4(0.f, 0.f, 0.f, 0.f);
        #pragma unroll
        for (int b = 0; b < 8; ++b) {
            float4 v = *(const float4*)&x[((size_t)b * NN + n0 + kr) * 64 + s4];
            ms.x += v.x; ms.y += v.y; ms.z += v.z; ms.w += v.w;
            v.x *= g.x; v.y *= g.y; v.z *= g.z; v.w *= g.w;
            *(float4*)&X[(size_t)(n0 + kr) * BSD + b * 64 + s4] = v;
            f16x4 h;
            h[0] = (_Float16)v.x; h[1] = (_Float16)v.y;
            h[2] = (_Float16)v.z; h[3] = (_Float16)v.w;
            *(f16x4*)&Lh[kr][b * 64 + s4] = h;
        }
        float4 mg4;
        mg4.x = ms.x * 0.125f * g.x; mg4.y = ms.y * 0.125f * g.y;
        mg4.z = ms.z * 0.125f * g.z; mg4.w = ms.w * 0.125f * g.w;
        *(float4*)&mg32[(size_t)(n0 + kr) * 64 + s4] = mg4;
        f16x4 mh, ml;
        mh[0] = (_Float16)mg4.x; ml[0] = (_Float16)(mg4.x - (float)mh[0]);
        mh[1] = (_Float16)mg4.y; ml[1] = (_Float16)(mg4.y - (float)mh[1]);
        mh[2] = (_Float16)mg4.z; ml[2] = (_Float16)(mg4.z - (float)mh[2]);
        mh[3] = (_Float16)mg4.w; ml[3] = (_Float16)(mg4.w - (float)mh[3]);
        *(f16x4*)&Nh[kr][s4] = mh;
        *(f16x4*)&Nl[kr][s4] = ml;
    }
    __syncthreads();
    pack_B(Lh, Nh, Nl, Bb, Nb, kt, t);
}

// ================================================================= gateconv (layers 2,3 B)
__global__ __launch_bounds__(256) void gateconv_kernel(float* __restrict__ X,
                                                       const float* __restrict__ gate,
                                                       const float* __restrict__ nsprev,
                                                       char* __restrict__ Bb,
                                                       char* __restrict__ Nb,
                                                       float* __restrict__ mg32) {
    __shared__ _Float16 Lh[64][520];
    __shared__ _Float16 Nh[64][72];
    __shared__ _Float16 Nl[64][72];
    const int t = threadIdx.x;
    const int kt = blockIdx.x;
    const int n0 = kt * 64;
    #pragma unroll
    for (int i = 0; i < 32; ++i) {
        int e = i * 256 + t;           // 0..8191
        int kr = e >> 7;               // 0..63
        int c4 = (e & 127) << 2;       // 0..508
        float4 v = *(const float4*)&X[(size_t)(n0 + kr) * BSD + c4];
        float4 g = *(const float4*)&gate[(size_t)(n0 + kr) * 64 + (c4 & 63)];
        v.x *= g.x; v.y *= g.y; v.z *= g.z; v.w *= g.w;
        *(float4*)&X[(size_t)(n0 + kr) * BSD + c4] = v;
        f16x4 h;
        h[0] = (_Float16)v.x; h[1] = (_Float16)v.y;
        h[2] = (_Float16)v.z; h[3] = (_Float16)v.w;
        *(f16x4*)&Lh[kr][c4] = h;
    }
    #pragma unroll
    for (int i = 0; i < 4; ++i) {
        int e = i * 256 + t;
        int kr = e >> 4;
        int s4 = (e & 15) << 2;
        float4 p = *(const float4*)&nsprev[(size_t)(n0 + kr) * 64 + s4];
        float4 g = *(const float4*)&gate[(size_t)(n0 + kr) * 64 + s4];
        float4 mg4;
        mg4.x = p.x * g.x; mg4.y = p.y * g.y; mg4.z = p.z * g.z; mg4.w = p.w * g.w;
        *(float4*)&mg32[(size_t)(n0 + kr) * 64 + s4] = mg4;
        f16x4 mh, ml;
        mh[0] = (_Float16)mg4.x; ml[0] = (_Float16)(mg4.x - (float)mh[0]);
        mh[1] = (_Float16)mg4.y; ml[1] = (_Float16)(mg4.y - (float)mh[1]);
        mh[2] = (_Float16)mg4.z; ml[2] = (_Float16)(mg4.z - (float)mh[2]);
        mh[3] = (_Float16)mg4.w; ml[3] = (_Float16)(mg4.w - (float)mh[3]);
        *(f16x4*)&Nh[kr][s4] = mh;
        *(f16x4*)&Nl[kr][s4] = ml;
    }
    __syncthreads();
    pack_B(Lh, Nh, Nl, Bb, Nb, kt, t);
}

// ================================================================= GEMM
// Main: X[m][c] = X_gated[m][c] + sum_k Dh[k][m]*Yg_f16[k][c]   (in-place X)
// ns:   ns[m][s] = mg[m][s] + sum_k (Dh*mh + Dh*ml + Dl*mh)[m][s]
// Block 64x(128+16ns), BK=64, 4 waves, grid 512 (2/CU).
// DEPTH-2 COUNTED PIPELINE (T4): 3 LDS slots for A, 3 register sets for B/N.
// Per-kt: vmcnt(12) [tile kt landed, kt+1 still in flight] ; s_barrier ;
// stage(kt+2) ; compute(kt).  Never vmcnt(0) until the tail.
__global__ __launch_bounds__(256, 2) void gemm_f16_kernel(const char* __restrict__ Ab,
                                                          const char* __restrict__ Bb,
                                                          const char* __restrict__ Nb,
                                                          float* X,
                                                          const float* __restrict__ mg,
                                                          float* __restrict__ nsout) {
    __shared__ char lds[3][16384];   // per slot: A hi 8K | A lo 8K
    const int t = threadIdx.x;
    const int L = blockIdx.x;                    // 0..511
    // XCD swizzle: the 4 nbt-blocks of one mt share an XCD (A panel L2 reuse)
    const int mt  = (L & 7) + ((L >> 5) << 3);   // 0..127 (64-row tile idx)
    const int nbt = (L >> 3) & 3;                // 0..3
    const int lane = t & 63, wid = t >> 6;       // 4 waves; wave cols = wid*32

    const char* gA = Ab + (((size_t)mt * 128) << 14) + wid * 2048 + lane * 16;
    const char* gB = Bb + (((size_t)nbt) << 14) + wid * 4096 + lane * 16;
    const char* gN = Nb + (((size_t)nbt) << 12) + lane * 16;
    const uint32_t lA = wid * 2048;

    // 3 register sets, constant-indexed only (rule 20)
    f16x8 B0[4], B1[4], B2[4], N0[4], N1[4], N2[4];

    // per tile per wave: exactly 12 VMEM ops (4 gload_lds + 4 B + 4 N)
    auto stage = [&](char* la, f16x8* Br, f16x8* Nr) {
        GLOAD_LDS16(gA,               la + lA);
        GLOAD_LDS16(gA + 1024,        la + lA + 1024);
        GLOAD_LDS16(gA + 8192,        la + lA + 8192);
        GLOAD_LDS16(gA + 8192 + 1024, la + lA + 8192 + 1024);
        Br[0] = *(const f16x8*)(gB);
        Br[1] = *(const f16x8*)(gB + 1024);
        Br[2] = *(const f16x8*)(gB + 2048);
        Br[3] = *(const f16x8*)(gB + 3072);
        Nr[0] = *(const f16x8*)(gN);
        Nr[1] = *(const f16x8*)(gN + 1024);
        Nr[2] = *(const f16x8*)(gN + 2048);
        Nr[3] = *(const f16x8*)(gN + 3072);
        gA += 16384; gB += 65536; gN += 16384;
    };

    f32x4 accm[4][2];
    #pragma unroll
    for (int fi = 0; fi < 4; ++fi) {
        accm[fi][0] = (f32x4){0.f, 0.f, 0.f, 0.f};
        accm[fi][1] = (f32x4){0.f, 0.f, 0.f, 0.f};
    }
    f32x4 accn = (f32x4){0.f, 0.f, 0.f, 0.f};

    auto compute = [&](const char* base, const f16x8* Br, const f16x8* Nr) {
        const char* A_ = base + lane * 16;          // +fi*2048+kk*1024 (+8192 lo)
        #pragma unroll
        for (int kk = 0; kk < 2; ++kk) {
            const int ko = kk * 1024;
            #pragma unroll
            for (int fi = 0; fi < 4; ++fi) {
                f16x8 ah = *(const f16x8*)(A_ + fi * 2048 + ko);
                accm[fi][0] = __builtin_amdgcn_mfma_f32_16x16x32_f16(ah, Br[kk],     accm[fi][0], 0, 0, 0);
                accm[fi][1] = __builtin_amdgcn_mfma_f32_16x16x32_f16(ah, Br[2 + kk], accm[fi][1], 0, 0, 0);
                if (fi == wid) {             // wave-uniform: ns rows = this wave's fi block
                    f16x8 aln = *(const f16x8*)(A_ + 8192 + fi * 2048 + ko);
                    accn = __builtin_amdgcn_mfma_f32_16x16x32_f16(ah,  Nr[kk],     accn, 0, 0, 0);
                    accn = __builtin_amdgcn_mfma_f32_16x16x32_f16(ah,  Nr[2 + kk], accn, 0, 0, 0);
                    accn = __builtin_amdgcn_mfma_f32_16x16x32_f16(aln, Nr[kk],     accn, 0, 0, 0);
                }
            }
        }
    };

#define PIPE_STEP(CURSLOT, BC, NC, PFSLOT, BP, NP)                      \
    asm volatile("s_waitcnt vmcnt(12)" ::: "memory");                   \
    __builtin_amdgcn_s_barrier();                                       \
    __builtin_amdgcn_sched_barrier(0);                                  \
    stage(lds[PFSLOT], BP, NP);                                         \
    __builtin_amdgcn_sched_barrier(0);                                  \
    compute(lds[CURSLOT], BC, NC);

    stage(lds[0], B0, N0);           // tile 0
    stage(lds[1], B1, N1);           // tile 1
    #pragma unroll 1
    for (int it = 0; it < 42; ++it) {        // kt = 3*it .. 3*it+2  (0..125)
        PIPE_STEP(0, B0, N0, 2, B2, N2)      // compute kt,   stage kt+2
        PIPE_STEP(1, B1, N1, 0, B0, N0)
        PIPE_STEP(2, B2, N2, 1, B1, N1)
    }
    // tail: kt = 126 (slot 0), kt = 127 (slot 1); no more staging
    asm volatile("s_waitcnt vmcnt(12)" ::: "memory");
    __builtin_amdgcn_s_barrier();
    __builtin_amdgcn_sched_barrier(0);
    compute(lds[0], B0, N0);
    asm volatile("s_waitcnt vmcnt(0)" ::: "memory");
    __builtin_amdgcn_s_barrier();
    __builtin_amdgcn_sched_barrier(0);
    compute(lds[1], B1, N1);
#undef PIPE_STEP

    // D layout (m89-verified): col = lane&15, row = (lane>>4)*4 + reg
    const int row0 = mt * 64 + ((lane >> 4) << 2);
    const int col0 = nbt * 128 + wid * 32 + (lane & 15);
    #pragma unroll
    for (int fi = 0; fi < 4; ++fi)
        #pragma unroll
        for (int fj = 0; fj < 2; ++fj)
            #pragma unroll
            for (int j = 0; j < 4; ++j) {
                size_t idx = (size_t)(row0 + fi * 16 + j) * BSD + col0 + fj * 16;
                X[idx] = accm[fi][fj][j] + X[idx];   // identity term (gated input, fp32)
            }
    const int nr0 = mt * 64 + wid * 16 + ((lane >> 4) << 2);
    const int nc  = nbt * 16 + (lane & 15);
    #pragma unroll
    for (int j = 0; j < 4; ++j) {
        size_t nidx = (size_t)(nr0 + j) * 64 + nc;
        nsout[nidx] = accn[j] + mg[nidx];            // identity term (gated mean, fp32)
    }
}

// ================================================================= readout
__global__ __launch_bounds__(256) void readout_kernel(const float* __restrict__ X3,
                                                      const float* __restrict__ W,
                                                      float* __restrict__ out) {
    __shared__ float Wt[64][65];
    __shared__ float xr[512];
    const int n = blockIdx.x;
    const int t = threadIdx.x;
    for (int e = t; e < 4096; e += 256) {
        int s = e >> 6, sp = e & 63;
        Wt[sp][s] = W[e];
    }
    xr[t]       = X3[(size_t)n * BSD + t];
    xr[t + 256] = X3[(size_t)n * BSD + 256 + t];
    __syncthreads();
    const int b1 = t >> 6;
    const int s  = t & 63;
    float acc0 = 0.0f, acc1 = 0.0f;
    #pragma unroll
    for (int sp = 0; sp < 64; ++sp) {
        float w = Wt[sp][s];
        acc0 += w * xr[b1 * 64 + sp];
        acc1 += w * xr[(b1 + 4) * 64 + sp];
    }
    out[((size_t)b1 * NN + n) * SS + s]       = acc0;
    out[((size_t)(b1 + 4) * NN + n) * SS + s] = acc1;
}

// ================================== temporal avg + enc + dec + top-k collapse
__global__ void nsfinal_kernel(const float* __restrict__ ns0,
                               const float* __restrict__ enc_w, const float* __restrict__ enc_b,
                               const float* __restrict__ dec_w, const float* __restrict__ dec_b,
                               float* __restrict__ out_ns) {
    int gtid = blockIdx.x * 256 + threadIdx.x;
    int lane = gtid & 63;
    const float r = 0.9f;
    const float wsum = 1.0f + r + r * r;
    float tns = (ns0[gtid] * (r * r) + ns0[NS + gtid] * r + ns0[2 * NS + gtid]) / wsum;
    float v = dec_b[lane];
    #pragma unroll
    for (int c = 0; c < 16; ++c) {
        float p = tns * enc_w[c * 64 + lane];
        #pragma unroll
        for (int off = 32; off; off >>= 1) p += __shfl_xor(p, off, 64);
        float h = fmaxf(p + enc_b[c], 0.0f);
        v += h * dec_w[lane * 16 + c];
    }
    float av = fabsf(v);
    int cnt = 0;
    for (int j = 0; j < 64; ++j) {
        float o = __shfl(av, j, 64);
        cnt += (o > av) ? 1 : 0;
    }
    out_ns[gtid] = (cnt < 8) ? v : 0.0f;
}

// ================================================================= launch
extern "C" void kernel_launch(void* const* d_in, const int* in_sizes, int n_in,
                              void* d_out, int out_size, void* d_ws, size_t ws_size,
                              hipStream_t stream) {
    const float* x      = (const float*)d_in[0];
    const float* ent    = (const float*)d_in[1];
    const float* mixing = (const float*)d_in[2];
    const float* r_w    = (const float*)d_in[3];
    const float* enc_w  = (const float*)d_in[4];
    const float* enc_b  = (const float*)d_in[5];
    const float* dec_w  = (const float*)d_in[6];
    const float* dec_b  = (const float*)d_in[7];
    float* out = (float*)d_out;

    char*  Ab   = (char*)d_ws;                    // 256 MB  (D hi|lo 64-row tiles)
    char*  Bb   = Ab + 268435456ull;              // 8 MB    (B main f16 tiles)
    char*  Nb   = Bb + 8388608ull;                // 2 MB    (B ns split tiles)
    float* X    = (float*)(Nb + 2097152ull);      // 16 MB   (activation, in-place)
    float* mg32 = X + NBS;                        // 2 MB    (gated mean fp32)
    float* ns0  = mg32 + NS;                      // 6 MB    (3 layer means)
    float* gate = ns0 + 3 * (size_t)NS;           // 2 MB

    sigmoid_gate_kernel<<<NS / 256, 256, 0, stream>>>(ent, gate);
    convA_kernel<<<dim3(128, 64), 256, 0, stream>>>(mixing, Ab);
    prep0_kernel<<<128, 256, 0, stream>>>(x, gate, X, Bb, Nb, mg32);

    for (int l = 0; l < 3; ++l) {
        gemm_f16_kernel<<<512, 256, 0, stream>>>(Ab, Bb, Nb, X, mg32, ns0 + (size_t)l * NS);
        if (l < 2)
            gateconv_kernel<<<128, 256, 0, stream>>>(X, gate, ns0 + (size_t)l * NS, Bb, Nb, mg32);
    }

    readout_kernel<<<NN, 256, 0, stream>>>(X, r_w, out);
    nsfinal_kernel<<<2048, 256, 0, stream>>>(ns0, enc_w, enc_b, dec_w, dec_b, out + NBS);
}

// Round 12
// 682.602 us; speedup vs baseline: 1.1817x; 1.1125x over previous
//
#include <hip/hip_runtime.h>

#define NN 8192
#define SS 64
#define BSD 512                 // B*S
#define NS (NN*SS)              // 524288
#define NBS (NN*BSD)            // 4194304

typedef __attribute__((ext_vector_type(4))) _Float16 f16x4;
typedef __attribute__((ext_vector_type(8))) _Float16 f16x8;
typedef __attribute__((ext_vector_type(4))) float f32x4;

#define GLOAD_LDS16(gptr, lptr) \
    __builtin_amdgcn_global_load_lds((const __attribute__((address_space(1))) void*)(gptr), \
                                     (__attribute__((address_space(3))) void*)(lptr), 16, 0, 0)

// claimed (lane,elem)->k map inside a 32-k chunk; only needs to be identical
// for A and B packs (self-canceling bijection in the MFMA dot product).
// Empirically validated by rounds 3/5/6/7/8/9/10/11 with random asymmetric Mix.
__device__ __forceinline__ int kmap(int lane, int e) {
    return ((lane >> 4) << 2) + (e & 3) + ((e >> 2) << 4);
}

// ---------------------------------------------------------------- gate
__global__ void sigmoid_gate_kernel(const float* __restrict__ ent, float* __restrict__ gate) {
    int i = blockIdx.x * 256 + threadIdx.x;
    gate[i] = 1.0f / (1.0f + expf(-ent[i]));
}

// ================================================================= convA
// D[k][m] = Mix[k][m] - (k==m), split hi/lo f16.
// 64-row tiles: tile(mt64,kt) at (mt64*128+kt)*16384: hi 8KB [blk4][kk2][lane][16B], lo +8192.
__global__ __launch_bounds__(256) void convA_kernel(const float* __restrict__ Mx,
                                                    char* __restrict__ Ab) {
    __shared__ _Float16 Lh[64][136];
    __shared__ _Float16 Ll[64][136];
    const int t = threadIdx.x;
    const int kt = blockIdx.x, mt = blockIdx.y;   // mt: 128-col group (0..63)
    const int k0 = kt * 64, m0 = mt * 128;
    #pragma unroll
    for (int i = 0; i < 8; ++i) {
        int e = i * 256 + t;
        int kr = e >> 5, m4 = (e & 31) << 2;
        float4 v = *(const float4*)&Mx[(size_t)(k0 + kr) * NN + m0 + m4];
        int d = (k0 + kr) - (m0 + m4);     // subtract identity where k == m
        if (d == 0) v.x -= 1.0f;
        if (d == 1) v.y -= 1.0f;
        if (d == 2) v.z -= 1.0f;
        if (d == 3) v.w -= 1.0f;
        f16x4 h, l;
        h[0] = (_Float16)v.x; l[0] = (_Float16)(v.x - (float)h[0]);
        h[1] = (_Float16)v.y; l[1] = (_Float16)(v.y - (float)h[1]);
        h[2] = (_Float16)v.z; l[2] = (_Float16)(v.z - (float)h[2]);
        h[3] = (_Float16)v.w; l[3] = (_Float16)(v.w - (float)h[3]);
        *(f16x4*)&Lh[kr][m4] = h;
        *(f16x4*)&Ll[kr][m4] = l;
    }
    __syncthreads();
    #pragma unroll
    for (int j = 0; j < 4; ++j) {
        int idx  = j * 256 + t;            // 0..1023
        int h    = idx >> 9;               // which 64-row half
        int w    = idx & 511;              // [blk4][kk2][lane64]
        int blk  = w >> 7;
        int kk   = (w >> 6) & 1;
        int lane = w & 63;
        int col  = h * 64 + blk * 16 + (lane & 15);
        int kb   = kk * 32;
        f16x8 hv, lv;
        #pragma unroll
        for (int e = 0; e < 8; ++e) {
            int k = kb + kmap(lane, e);
            hv[e] = Lh[k][col];
            lv[e] = Ll[k][col];
        }
        char* tile = Ab + (((size_t)(mt * 2 + h) * 128 + kt) << 14);
        *(f16x8*)(tile + w * 16)        = hv;
        *(f16x8*)(tile + 8192 + w * 16) = lv;
    }
}

// ---------------------------------------------------------------- shared B pack
__device__ __forceinline__ void pack_B(const _Float16 (*Lh)[520],
                                       const _Float16 (*Nh)[72], const _Float16 (*Nl)[72],
                                       char* Bb, char* Nb, int kt, int t) {
    #pragma unroll
    for (int j = 0; j < 16; ++j) {
        int idx = j * 256 + t;             // 0..4095
        int nbt = idx >> 10, w = idx & 1023;
        int blk = w >> 7, kk = (w >> 6) & 1, lane = w & 63;
        int col = nbt * 128 + blk * 16 + (lane & 15);
        int kb = kk * 32;
        f16x8 hv;
        #pragma unroll
        for (int e = 0; e < 8; ++e)
            hv[e] = Lh[kb + kmap(lane, e)][col];
        *(f16x8*)(Bb + (((size_t)kt * 4 + nbt) << 14) + w * 16) = hv;
    }
    #pragma unroll
    for (int j = 0; j < 4; ++j) {
        int idx = j * 256 + t;             // 0..1023
        int nbt = idx >> 8, r = idx & 255;
        int part = r >> 7, kk = (r >> 6) & 1, lane = r & 63;
        int s = nbt * 16 + (lane & 15);
        int kb = kk * 32;
        f16x8 v;
        #pragma unroll
        for (int e = 0; e < 8; ++e) {
            int k = kb + kmap(lane, e);
            v[e] = part ? Nl[k][s] : Nh[k][s];
        }
        *(f16x8*)(Nb + (((size_t)kt * 4 + nbt) << 12) + part * 2048 + kk * 1024 + lane * 16) = v;
    }
}

// ================================================================= prep0 (layer 1 B)
__global__ __launch_bounds__(256) void prep0_kernel(const float* __restrict__ x,
                                                    const float* __restrict__ gate,
                                                    float* __restrict__ X,
                                                    char* __restrict__ Bb,
                                                    char* __restrict__ Nb,
                                                    float* __restrict__ mg32) {
    __shared__ _Float16 Lh[64][520];
    __shared__ _Float16 Nh[64][72];
    __shared__ _Float16 Nl[64][72];
    const int t = threadIdx.x;
    const int kt = blockIdx.x;
    const int n0 = kt * 64;
    #pragma unroll
    for (int i = 0; i < 4; ++i) {
        int e = i * 256 + t;           // 0..1023
        int kr = e >> 4;               // 0..63
        int s4 = (e & 15) << 2;        // 0..60
        float4 g = *(const float4*)&gate[(size_t)(n0 + kr) * 64 + s4];
        float4 ms = make_float4(0.f, 0.f, 0.f, 0.f);
        #pragma unroll
        for (int b = 0; b < 8; ++b) {
            float4 v = *(const float4*)&x[((size_t)b * NN + n0 + kr) * 64 + s4];
            ms.x += v.x; ms.y += v.y; ms.z += v.z; ms.w += v.w;
            v.x *= g.x; v.y *= g.y; v.z *= g.z; v.w *= g.w;
            *(float4*)&X[(size_t)(n0 + kr) * BSD + b * 64 + s4] = v;
            f16x4 h;
            h[0] = (_Float16)v.x; h[1] = (_Float16)v.y;
            h[2] = (_Float16)v.z; h[3] = (_Float16)v.w;
            *(f16x4*)&Lh[kr][b * 64 + s4] = h;
        }
        float4 mg4;
        mg4.x = ms.x * 0.125f * g.x; mg4.y = ms.y * 0.125f * g.y;
        mg4.z = ms.z * 0.125f * g.z; mg4.w = ms.w * 0.125f * g.w;
        *(float4*)&mg32[(size_t)(n0 + kr) * 64 + s4] = mg4;
        f16x4 mh, ml;
        mh[0] = (_Float16)mg4.x; ml[0] = (_Float16)(mg4.x - (float)mh[0]);
        mh[1] = (_Float16)mg4.y; ml[1] = (_Float16)(mg4.y - (float)mh[1]);
        mh[2] = (_Float16)mg4.z; ml[2] = (_Float16)(mg4.z - (float)mh[2]);
        mh[3] = (_Float16)mg4.w; ml[3] = (_Float16)(mg4.w - (float)mh[3]);
        *(f16x4*)&Nh[kr][s4] = mh;
        *(f16x4*)&Nl[kr][s4] = ml;
    }
    __syncthreads();
    pack_B(Lh, Nh, Nl, Bb, Nb, kt, t);
}

// ================================================================= gateconv (layers 2,3 B)
__global__ __launch_bounds__(256) void gateconv_kernel(float* __restrict__ X,
                                                       const float* __restrict__ gate,
                                                       const float* __restrict__ nsprev,
                                                       char* __restrict__ Bb,
                                                       char* __restrict__ Nb,
                                                       float* __restrict__ mg32) {
    __shared__ _Float16 Lh[64][520];
    __shared__ _Float16 Nh[64][72];
    __shared__ _Float16 Nl[64][72];
    const int t = threadIdx.x;
    const int kt = blockIdx.x;
    const int n0 = kt * 64;
    #pragma unroll
    for (int i = 0; i < 32; ++i) {
        int e = i * 256 + t;           // 0..8191
        int kr = e >> 7;               // 0..63
        int c4 = (e & 127) << 2;       // 0..508
        float4 v = *(const float4*)&X[(size_t)(n0 + kr) * BSD + c4];
        float4 g = *(const float4*)&gate[(size_t)(n0 + kr) * 64 + (c4 & 63)];
        v.x *= g.x; v.y *= g.y; v.z *= g.z; v.w *= g.w;
        *(float4*)&X[(size_t)(n0 + kr) * BSD + c4] = v;
        f16x4 h;
        h[0] = (_Float16)v.x; h[1] = (_Float16)v.y;
        h[2] = (_Float16)v.z; h[3] = (_Float16)v.w;
        *(f16x4*)&Lh[kr][c4] = h;
    }
    #pragma unroll
    for (int i = 0; i < 4; ++i) {
        int e = i * 256 + t;
        int kr = e >> 4;
        int s4 = (e & 15) << 2;
        float4 p = *(const float4*)&nsprev[(size_t)(n0 + kr) * 64 + s4];
        float4 g = *(const float4*)&gate[(size_t)(n0 + kr) * 64 + s4];
        float4 mg4;
        mg4.x = p.x * g.x; mg4.y = p.y * g.y; mg4.z = p.z * g.z; mg4.w = p.w * g.w;
        *(float4*)&mg32[(size_t)(n0 + kr) * 64 + s4] = mg4;
        f16x4 mh, ml;
        mh[0] = (_Float16)mg4.x; ml[0] = (_Float16)(mg4.x - (float)mh[0]);
        mh[1] = (_Float16)mg4.y; ml[1] = (_Float16)(mg4.y - (float)mh[1]);
        mh[2] = (_Float16)mg4.z; ml[2] = (_Float16)(mg4.z - (float)mh[2]);
        mh[3] = (_Float16)mg4.w; ml[3] = (_Float16)(mg4.w - (float)mh[3]);
        *(f16x4*)&Nh[kr][s4] = mh;
        *(f16x4*)&Nl[kr][s4] = ml;
    }
    __syncthreads();
    pack_B(Lh, Nh, Nl, Bb, Nb, kt, t);
}

// ================================================================= GEMM
// Main: X[m][c] = X_gated[m][c] + sum_k Dh[k][m]*Yg_f16[k][c]   (in-place X)
// ns:   ns[m][s] = mg[m][s] + sum_k (Dh*mh + Dh*ml + Dl*mh)[m][s]
// Block 64x(128+16ns), BK=128 (64 super-tiles = two 16KB kt-tiles, contiguous),
// 4 waves, grid 512 (2/CU).  A hi+lo + ns-B via LDS (dbuf 2x40KB = 80KB);
// B-main direct L2->VGPR.  R6-proven 2-barrier counted schedule, half the
// iterations: stage(next) ; vmcnt(18) ; barrier ; compute(cur) ; barrier.
__global__ __launch_bounds__(256, 2) void gemm_f16_kernel(const char* __restrict__ Ab,
                                                          const char* __restrict__ Bb,
                                                          const char* __restrict__ Nb,
                                                          float* X,
                                                          const float* __restrict__ mg,
                                                          float* __restrict__ nsout) {
    __shared__ char lds[2][40960];   // A super-tile 32KB (hi0|lo0|hi1|lo1) | N 8KB
    const int t = threadIdx.x;
    const int L = blockIdx.x;                    // 0..511
    // XCD swizzle: the 4 nbt-blocks of one mt share an XCD (A panel L2 reuse)
    const int mt  = (L & 7) + ((L >> 5) << 3);   // 0..127 (64-row tile idx)
    const int nbt = (L >> 3) & 3;                // 0..3
    const int lane = t & 63, wid = t >> 6;       // 4 waves; wave cols = wid*32

    // running pointers; strides per super-tile: A 32KB, B 128KB, N 32KB
    const char* gA = Ab + (((size_t)mt * 128) << 14) + wid * 2048 + lane * 16;
    const char* gB = Bb + (((size_t)nbt) << 14) + wid * 4096 + lane * 16;
    const char* gN = Nb + (((size_t)nbt) << 12) + wid * 1024 + lane * 16;
    const uint32_t lA = wid * 2048;
    const uint32_t lN = 32768 + wid * 1024;

    f16x8 B0[8], B1[8];      // constant-indexed only (rule 20)

    // per wave per super-tile: 10 global_load_lds + 8 reg loads = 18 VMEM
    auto stage = [&](char* la, f16x8* Br) {
        GLOAD_LDS16(gA,                       la + lA);
        GLOAD_LDS16(gA + 1024,                la + lA + 1024);
        GLOAD_LDS16(gA + 8192,                la + lA + 8192);
        GLOAD_LDS16(gA + 8192 + 1024,         la + lA + 8192 + 1024);
        GLOAD_LDS16(gA + 16384,               la + 16384 + lA);
        GLOAD_LDS16(gA + 16384 + 1024,        la + 16384 + lA + 1024);
        GLOAD_LDS16(gA + 16384 + 8192,        la + 16384 + lA + 8192);
        GLOAD_LDS16(gA + 16384 + 8192 + 1024, la + 16384 + lA + 8192 + 1024);
        GLOAD_LDS16(gN,                       la + lN);
        GLOAD_LDS16(gN + 16384,               la + lN + 4096);
        Br[0] = *(const f16x8*)(gB);
        Br[1] = *(const f16x8*)(gB + 1024);
        Br[2] = *(const f16x8*)(gB + 2048);
        Br[3] = *(const f16x8*)(gB + 3072);
        Br[4] = *(const f16x8*)(gB + 65536);
        Br[5] = *(const f16x8*)(gB + 65536 + 1024);
        Br[6] = *(const f16x8*)(gB + 65536 + 2048);
        Br[7] = *(const f16x8*)(gB + 65536 + 3072);
        gA += 32768; gB += 131072; gN += 32768;
    };

    f32x4 accm[4][2];
    #pragma unroll
    for (int fi = 0; fi < 4; ++fi) {
        accm[fi][0] = (f32x4){0.f, 0.f, 0.f, 0.f};
        accm[fi][1] = (f32x4){0.f, 0.f, 0.f, 0.f};
    }
    f32x4 accn = (f32x4){0.f, 0.f, 0.f, 0.f};

    auto compute = [&](const char* base, const f16x8* Br) {
        const char* A_ = base + lane * 16;
        const char* N_ = base + 32768 + lane * 16;
        #pragma unroll
        for (int kk = 0; kk < 4; ++kk) {                 // four 32-k chunks
            const int ao = (kk >> 1) * 16384 + (kk & 1) * 1024;   // A half + sub
            const int no = (kk >> 1) * 4096 + (kk & 1) * 1024;    // N half + sub
            const int bi = (kk >> 1) * 4 + (kk & 1);              // B reg idx
            f16x8 bnh = *(const f16x8*)(N_ + no);
            f16x8 bnl = *(const f16x8*)(N_ + no + 2048);
            #pragma unroll
            for (int fi = 0; fi < 4; ++fi) {
                f16x8 ah = *(const f16x8*)(A_ + ao + fi * 2048);
                accm[fi][0] = __builtin_amdgcn_mfma_f32_16x16x32_f16(ah, Br[bi],     accm[fi][0], 0, 0, 0);
                accm[fi][1] = __builtin_amdgcn_mfma_f32_16x16x32_f16(ah, Br[bi + 2], accm[fi][1], 0, 0, 0);
                if (fi == wid) {             // wave-uniform: ns rows = this wave's fi block
                    f16x8 aln = *(const f16x8*)(A_ + ao + 8192 + fi * 2048);
                    accn = __builtin_amdgcn_mfma_f32_16x16x32_f16(ah,  bnh, accn, 0, 0, 0);
                    accn = __builtin_amdgcn_mfma_f32_16x16x32_f16(ah,  bnl, accn, 0, 0, 0);
                    accn = __builtin_amdgcn_mfma_f32_16x16x32_f16(aln, bnh, accn, 0, 0, 0);
                }
            }
        }
    };

    stage(lds[0], B0);                       // super-tile 0
    for (int u = 0; u < 32; ++u) {
        // ---- even super-tile 2u: prefetch 2u+1, compute 2u
        stage(lds[1], B1);
        asm volatile("s_waitcnt vmcnt(18)" ::: "memory");   // tile 2u landed
        __builtin_amdgcn_s_barrier();
        compute(lds[0], B0);
        __builtin_amdgcn_s_barrier();                       // all reads of slot0 done
        // ---- odd super-tile 2u+1: prefetch 2u+2, compute 2u+1
        if (u < 31) {
            stage(lds[0], B0);
            asm volatile("s_waitcnt vmcnt(18)" ::: "memory");
        } else {
            asm volatile("s_waitcnt vmcnt(0)" ::: "memory");
        }
        __builtin_amdgcn_s_barrier();
        compute(lds[1], B1);
        __builtin_amdgcn_s_barrier();                       // all reads of slot1 done
    }

    // D layout (m89-verified): col = lane&15, row = (lane>>4)*4 + reg
    const int row0 = mt * 64 + ((lane >> 4) << 2);
    const int col0 = nbt * 128 + wid * 32 + (lane & 15);
    #pragma unroll
    for (int fi = 0; fi < 4; ++fi)
        #pragma unroll
        for (int fj = 0; fj < 2; ++fj)
            #pragma unroll
            for (int j = 0; j < 4; ++j) {
                size_t idx = (size_t)(row0 + fi * 16 + j) * BSD + col0 + fj * 16;
                X[idx] = accm[fi][fj][j] + X[idx];   // identity term (gated input, fp32)
            }
    const int nr0 = mt * 64 + wid * 16 + ((lane >> 4) << 2);
    const int nc  = nbt * 16 + (lane & 15);
    #pragma unroll
    for (int j = 0; j < 4; ++j) {
        size_t nidx = (size_t)(nr0 + j) * 64 + nc;
        nsout[nidx] = accn[j] + mg[nidx];            // identity term (gated mean, fp32)
    }
}

// ================================================================= readout
__global__ __launch_bounds__(256) void readout_kernel(const float* __restrict__ X3,
                                                      const float* __restrict__ W,
                                                      float* __restrict__ out) {
    __shared__ float Wt[64][65];
    __shared__ float xr[512];
    const int n = blockIdx.x;
    const int t = threadIdx.x;
    for (int e = t; e < 4096; e += 256) {
        int s = e >> 6, sp = e & 63;
        Wt[sp][s] = W[e];
    }
    xr[t]       = X3[(size_t)n * BSD + t];
    xr[t + 256] = X3[(size_t)n * BSD + 256 + t];
    __syncthreads();
    const int b1 = t >> 6;
    const int s  = t & 63;
    float acc0 = 0.0f, acc1 = 0.0f;
    #pragma unroll
    for (int sp = 0; sp < 64; ++sp) {
        float w = Wt[sp][s];
        acc0 += w * xr[b1 * 64 + sp];
        acc1 += w * xr[(b1 + 4) * 64 + sp];
    }
    out[((size_t)b1 * NN + n) * SS + s]       = acc0;
    out[((size_t)(b1 + 4) * NN + n) * SS + s] = acc1;
}

// ================================== temporal avg + enc + dec + top-k collapse
__global__ void nsfinal_kernel(const float* __restrict__ ns0,
                               const float* __restrict__ enc_w, const float* __restrict__ enc_b,
                               const float* __restrict__ dec_w, const float* __restrict__ dec_b,
                               float* __restrict__ out_ns) {
    int gtid = blockIdx.x * 256 + threadIdx.x;
    int lane = gtid & 63;
    const float r = 0.9f;
    const float wsum = 1.0f + r + r * r;
    float tns = (ns0[gtid] * (r * r) + ns0[NS + gtid] * r + ns0[2 * NS + gtid]) / wsum;
    float v = dec_b[lane];
    #pragma unroll
    for (int c = 0; c < 16; ++c) {
        float p = tns * enc_w[c * 64 + lane];
        #pragma unroll
        for (int off = 32; off; off >>= 1) p += __shfl_xor(p, off, 64);
        float h = fmaxf(p + enc_b[c], 0.0f);
        v += h * dec_w[lane * 16 + c];
    }
    float av = fabsf(v);
    int cnt = 0;
    for (int j = 0; j < 64; ++j) {
        float o = __shfl(av, j, 64);
        cnt += (o > av) ? 1 : 0;
    }
    out_ns[gtid] = (cnt < 8) ? v : 0.0f;
}

// ================================================================= launch
extern "C" void kernel_launch(void* const* d_in, const int* in_sizes, int n_in,
                              void* d_out, int out_size, void* d_ws, size_t ws_size,
                              hipStream_t stream) {
    const float* x      = (const float*)d_in[0];
    const float* ent    = (const float*)d_in[1];
    const float* mixing = (const float*)d_in[2];
    const float* r_w    = (const float*)d_in[3];
    const float* enc_w  = (const float*)d_in[4];
    const float* enc_b  = (const float*)d_in[5];
    const float* dec_w  = (const float*)d_in[6];
    const float* dec_b  = (const float*)d_in[7];
    float* out = (float*)d_out;

    char*  Ab   = (char*)d_ws;                    // 256 MB  (D hi|lo 64-row tiles)
    char*  Bb   = Ab + 268435456ull;              // 8 MB    (B main f16 tiles)
    char*  Nb   = Bb + 8388608ull;                // 2 MB    (B ns split tiles)
    float* X    = (float*)(Nb + 2097152ull);      // 16 MB   (activation, in-place)
    float* mg32 = X + NBS;                        // 2 MB    (gated mean fp32)
    float* ns0  = mg32 + NS;                      // 6 MB    (3 layer means)
    float* gate = ns0 + 3 * (size_t)NS;           // 2 MB

    sigmoid_gate_kernel<<<NS / 256, 256, 0, stream>>>(ent, gate);
    convA_kernel<<<dim3(128, 64), 256, 0, stream>>>(mixing, Ab);
    prep0_kernel<<<128, 256, 0, stream>>>(x, gate, X, Bb, Nb, mg32);

    for (int l = 0; l < 3; ++l) {
        gemm_f16_kernel<<<512, 256, 0, stream>>>(Ab, Bb, Nb, X, mg32, ns0 + (size_t)l * NS);
        if (l < 2)
            gateconv_kernel<<<128, 256, 0, stream>>>(X, gate, ns0 + (size_t)l * NS, Bb, Nb, mg32);
    }

    readout_kernel<<<NN, 256, 0, stream>>>(X, r_w, out);
    nsfinal_kernel<<<2048, 256, 0, stream>>>(ns0, enc_w, enc_b, dec_w, dec_b, out + NBS);
}